// Round 1
// baseline (601.270 us; speedup 1.0000x reference)
//
#include <hip/hip_runtime.h>
#include <hip/hip_bf16.h>

typedef unsigned short u16;

#define M_ROWS 8192
#define N_ROWS 16384
#define KDIM   512
#define BM     128
#define BN     128
#define BK     64
#define NCHUNKS 8
#define NPER   (N_ROWS / NCHUNKS)   /* 2048 */
#define TOPK   9

typedef __attribute__((ext_vector_type(8))) short bf16x8;
typedef __attribute__((ext_vector_type(4))) float f32x4;

__device__ __forceinline__ void gload_lds16(const void* g, void* l) {
  __builtin_amdgcn_global_load_lds(
      (const __attribute__((address_space(1))) void*)g,
      (__attribute__((address_space(3))) void*)l,
      16, 0, 0);
}

__device__ __forceinline__ u16 f2bf(float x) {
  union { float f; unsigned u; } c; c.f = x;
  unsigned u = c.u;
  u += 0x7fffu + ((u >> 16) & 1u);   // RNE; inputs are finite randn, no NaN handling needed
  return (u16)(u >> 16);
}

__device__ __forceinline__ void topk_update(float v, float best[TOPK]) {
  if (v < best[TOPK - 1]) {
    #pragma unroll
    for (int i = 0; i < TOPK; ++i) {
      float b = best[i];
      best[i] = fminf(b, v);
      v = fmaxf(b, v);
    }
  }
}

// ---------------- Kernel 1: fp32 -> bf16 convert + fp32 row norms ----------------
__global__ __launch_bounds__(128) void prep_kernel(
    const float* __restrict__ fv, const float* __restrict__ mb,
    u16* __restrict__ fvb, u16* __restrict__ mbb,
    float* __restrict__ nf, float* __restrict__ nm)
{
  int id = blockIdx.x;
  const float* src; u16* dst; float* nrm;
  if (id < M_ROWS) {
    src = fv + (size_t)id * KDIM; dst = fvb + (size_t)id * KDIM; nrm = nf + id;
  } else {
    int r = id - M_ROWS;
    src = mb + (size_t)r * KDIM; dst = mbb + (size_t)r * KDIM; nrm = nm + r;
  }
  int t = threadIdx.x;            // 128 threads, 4 floats each = 512
  float4 x = ((const float4*)src)[t];
  float s = x.x * x.x + x.y * x.y + x.z * x.z + x.w * x.w;
  ushort4 o;
  o.x = f2bf(x.x); o.y = f2bf(x.y); o.z = f2bf(x.z); o.w = f2bf(x.w);
  ((ushort4*)dst)[t] = o;
  #pragma unroll
  for (int off = 32; off > 0; off >>= 1) s += __shfl_down(s, off, 64);
  __shared__ float red[2];
  if ((t & 63) == 0) red[t >> 6] = s;
  __syncthreads();
  if (t == 0) nrm[0] = red[0] + red[1];
}

// ------------- Kernel 2: bf16 MFMA GEMM (A.B^T) + fused per-row top-9 -------------
// grid (64, 8), block 256 (4 waves). Each block: 128 M-rows x 2048 N-cols.
// Ranks val = nm[j] - 2*dot (nf_i per-row constant -> deferred; order-preserving).
__global__ __launch_bounds__(256) void gemm_topk_kernel(
    const u16* __restrict__ fvb, const u16* __restrict__ mbb,
    const float* __restrict__ nm, float* __restrict__ partial)
{
  __shared__ __align__(16) u16 As[BM * BK];     // [128][64] bf16, 16 KB
  __shared__ __align__(16) u16 Bs[BN * BK];     // 16 KB
  __shared__ __align__(16) float Sq[128 * 66];  // 128 rows x 64 cols (+2 pad), 33.8 KB

  const int t    = threadIdx.x;
  const int l    = t & 63;
  const int w    = t >> 6;
  const int wm   = w & 1;        // wave m-quadrant (0/1 -> rows 0..63 / 64..127)
  const int wn   = w >> 1;       // wave n-quadrant
  const int quad = l >> 4;
  const int l15  = l & 15;

  const int m0    = blockIdx.x * BM;
  const int ncoff = blockIdx.y * NPER;

  // staging: wave w covers chunk rows w*32 .. w*32+31, 8 rows per 64-lane load
  const int srow = w * 32 + (l >> 3);
  const int scol = (l & 7) * 8;   // bf16 element offset within BK

  float best[TOPK];
  #pragma unroll
  for (int i = 0; i < TOPK; ++i) best[i] = 3.4e38f;

  const int scan_row = t & 127;   // row this thread ranks
  const int half     = t >> 7;    // which 32-col half of each 64-col pass

  for (int nt = 0; nt < NPER / BN; ++nt) {
    const int nbase = ncoff + nt * BN;
    f32x4 acc[4][4];
    #pragma unroll
    for (int i = 0; i < 4; ++i)
      #pragma unroll
      for (int j = 0; j < 4; ++j) acc[i][j] = (f32x4){0.f, 0.f, 0.f, 0.f};

    for (int kc = 0; kc < KDIM / BK; ++kc) {
      __syncthreads();            // previous readers of As/Bs (and Sq scan) done
      const int kb = kc * BK + scol;
      #pragma unroll
      for (int i = 0; i < 4; ++i) {
        gload_lds16(fvb + (size_t)(m0 + srow + i * 8) * KDIM + kb,
                    &As[(w * 32 + i * 8) * BK]);
        gload_lds16(mbb + (size_t)(nbase + srow + i * 8) * KDIM + kb,
                    &Bs[(w * 32 + i * 8) * BK]);
      }
      __syncthreads();            // barrier drains vmcnt -> LDS data visible
      #pragma unroll
      for (int ks = 0; ks < 2; ++ks) {
        bf16x8 af[4], bf[4];
        #pragma unroll
        for (int i = 0; i < 4; ++i) {
          af[i] = *(const bf16x8*)&As[(wm * 64 + i * 16 + l15) * BK + ks * 32 + quad * 8];
          bf[i] = *(const bf16x8*)&Bs[(wn * 64 + i * 16 + l15) * BK + ks * 32 + quad * 8];
        }
        #pragma unroll
        for (int i = 0; i < 4; ++i)
          #pragma unroll
          for (int j = 0; j < 4; ++j)
            acc[i][j] = __builtin_amdgcn_mfma_f32_16x16x32_bf16(af[i], bf[j], acc[i][j], 0, 0, 0);
      }
    }

    // epilogue: two 128x64 passes through LDS, fused top-9 scan
    #pragma unroll
    for (int p = 0; p < 2; ++p) {
      __syncthreads();            // Sq free (previous scan done)
      if (wn == p) {
        #pragma unroll
        for (int j = 0; j < 4; ++j) {
          float nmv = nm[nbase + p * 64 + j * 16 + l15];
          #pragma unroll
          for (int i = 0; i < 4; ++i) {
            #pragma unroll
            for (int r = 0; r < 4; ++r) {
              int row = wm * 64 + i * 16 + quad * 4 + r;  // C/D: row=quad*4+reg, col=lane&15
              Sq[row * 66 + j * 16 + l15] = nmv - 2.0f * acc[i][j][r];
            }
          }
        }
      }
      __syncthreads();
      const float* rowp = &Sq[scan_row * 66 + half * 32];
      #pragma unroll
      for (int j = 0; j < 32; j += 2) {
        float2 v2 = *(const float2*)(rowp + j);
        topk_update(v2.x, best);
        topk_update(v2.y, best);
      }
    }
  }

  // 16 partial lists per row: (nchunk, half)
  size_t base = ((size_t)(blockIdx.y * 2 + half) * M_ROWS + (m0 + scan_row)) * TOPK;
  #pragma unroll
  for (int i = 0; i < TOPK; ++i) partial[base + i] = best[i];
}

// ---------------- Kernel 3: merge 16 partial lists/row, sqrt, pixel scores ----------------
__global__ __launch_bounds__(256) void merge_kernel(
    const float* __restrict__ partial, const float* __restrict__ nf,
    float* __restrict__ final9, float* __restrict__ out_pix)
{
  int row = blockIdx.x * 256 + threadIdx.x;   // 8192 rows
  float best[TOPK];
  #pragma unroll
  for (int i = 0; i < TOPK; ++i) best[i] = 3.4e38f;
  for (int s = 0; s < 2 * NCHUNKS; ++s) {
    const float* p = &partial[((size_t)s * M_ROWS + row) * TOPK];
    #pragma unroll
    for (int i = 0; i < TOPK; ++i) topk_update(p[i], best);
  }
  float nfr = nf[row];
  float d[TOPK];
  #pragma unroll
  for (int i = 0; i < TOPK; ++i) d[i] = sqrtf(fmaxf(best[i] + nfr, 0.0f));
  out_pix[row] = d[0];
  #pragma unroll
  for (int i = 0; i < TOPK; ++i) final9[(size_t)row * TOPK + i] = d[i];
}

// ---------------- Kernel 4: per-image argmax (first-max) + softmax score ----------------
__global__ __launch_bounds__(256) void img_kernel(
    const float* __restrict__ out_pix, const float* __restrict__ final9,
    const int* __restrict__ bptr, float* __restrict__ out_img)
{
  int img = blockIdx.x, t = threadIdx.x;
  float bv = -1.0f; int bi = 0;
  for (int p = t; p < 1024; p += 256) {
    float v = out_pix[img * 1024 + p];
    if (v > bv) { bv = v; bi = p; }           // ascending p -> keeps first max in-thread
  }
  __shared__ float sv[256];
  __shared__ int   si[256];
  sv[t] = bv; si[t] = bi;
  __syncthreads();
  for (int off = 128; off > 0; off >>= 1) {
    if (t < off) {
      float v2 = sv[t + off]; int i2 = si[t + off];
      if (v2 > sv[t] || (v2 == sv[t] && i2 < si[t])) { sv[t] = v2; si[t] = i2; }
    }
    __syncthreads();
  }
  if (t == 0) {
    int row = img * 1024 + si[0];
    int b = bptr[0];
    float s0 = final9[(size_t)row * TOPK + 0];
    float score = s0;
    if (b > 1) {
      int bb = b < TOPK ? b : TOPK;
      float mx = s0;
      for (int i = 1; i < bb; ++i) mx = fmaxf(mx, final9[(size_t)row * TOPK + i]);
      float den = 0.0f;
      for (int i = 0; i < bb; ++i) den += expf(final9[(size_t)row * TOPK + i] - mx);
      score = s0 * (1.0f - expf(s0 - mx) / den);
    }
    out_img[img] = score;
  }
}

extern "C" void kernel_launch(void* const* d_in, const int* in_sizes, int n_in,
                              void* d_out, int out_size, void* d_ws, size_t ws_size,
                              hipStream_t stream) {
  const float* fv   = (const float*)d_in[0];
  const float* mb   = (const float*)d_in[1];
  const int*   bptr = (const int*)d_in[2];
  float* out = (float*)d_out;

  char* w = (char*)d_ws;
  u16*   fvb     = (u16*)w;                        // 8192*512*2  = 8388608 B
  u16*   mbb     = (u16*)(w + 8388608);            // 16384*512*2 = 16777216 B
  float* nf      = (float*)(w + 25165824);         // 32768 B
  float* nm      = (float*)(w + 25198592);         // 65536 B
  float* partial = (float*)(w + 25264128);         // 16*8192*9*4 = 4718592 B
  float* final9  = (float*)(w + 29982720);         // 8192*9*4    = 294912 B
                                                   // total ~30.3 MB of ws

  hipLaunchKernelGGL(prep_kernel, dim3(M_ROWS + N_ROWS), dim3(128), 0, stream,
                     fv, mb, fvb, mbb, nf, nm);
  hipLaunchKernelGGL(gemm_topk_kernel, dim3(M_ROWS / BM, NCHUNKS), dim3(256), 0, stream,
                     fvb, mbb, nm, partial);
  hipLaunchKernelGGL(merge_kernel, dim3(M_ROWS / 256), dim3(256), 0, stream,
                     partial, nf, final9, out);
  hipLaunchKernelGGL(img_kernel, dim3(8), dim3(256), 0, stream,
                     out, final9, bptr, out + M_ROWS);
}